// Round 7
// baseline (202.663 us; speedup 1.0000x reference)
//
#include <hip/hip_runtime.h>
#include <cmath>

// Shapes fixed by the reference: data [32,128,80,80] int32, scale 0.0625.
#define NB  32
#define NC  128
#define NHW 6400            // 80*80, contiguous per (b,c)
#define PIX 64              // pixels per block
#define TPB 256             // 16 pixel-quads x 16 channel-groups
#define BPB (NHW / PIX)     // 100 blocks per image

typedef float vfloat4 __attribute__((ext_vector_type(4)));

// Thread t: k = t&15 owns channels {k, k+16, ..., k+112};
//           q = t>>4 owns pixels {4q .. 4q+3} (one int4/float4 per channel).
// k occupies the LOW 4 lane bits -> the 16 lanes sharing a pixel-quad are one
// DPP row: max/sum reductions are VALU DPP butterflies (no LDS, no barriers).
// DS pipe carries ONLY the 32 exp-gathers per thread. One barrier total.

template <int CTRL>
__device__ __forceinline__ int dpp_mov(int x) {
  return __builtin_amdgcn_update_dpp(x, x, CTRL, 0xF, 0xF, true);
}
#define DPP_XOR1 0xB1   // quad_perm [1,0,3,2]
#define DPP_XOR2 0x4E   // quad_perm [2,3,0,1]
#define DPP_ROR4 0x124  // row_ror:4
#define DPP_ROR8 0x128  // row_ror:8

template <int CTRL>
__device__ __forceinline__ void dpp_max4(int4& m) {
  m.x = max(m.x, dpp_mov<CTRL>(m.x));
  m.y = max(m.y, dpp_mov<CTRL>(m.y));
  m.z = max(m.z, dpp_mov<CTRL>(m.z));
  m.w = max(m.w, dpp_mov<CTRL>(m.w));
}
template <int CTRL>
__device__ __forceinline__ void dpp_add4(int4& s) {
  s.x += dpp_mov<CTRL>(s.x);
  s.y += dpp_mov<CTRL>(s.y);
  s.z += dpp_mov<CTRL>(s.z);
  s.w += dpp_mov<CTRL>(s.w);
}

__global__ __launch_bounds__(TPB) void qsoftmax_kernel(
    const int* __restrict__ data,
    const float* __restrict__ dscale,
    float* __restrict__ out) {
#pragma clang fp contract(off)
  __shared__ float exp_tab_f[256];   // quantized exp (integer-valued float)
  __shared__ float recip_tab[256];   // quantized 1/v table, region (0.1, 250)

  const int t = threadIdx.x;
  const int k = t & 15;
  const int q = t >> 4;

  const float ds = dscale[0];        // 0.0625

  // ---- build LUTs: thread t builds entry t (identical math to absmax=0) ----
  {
    const float EXP_SCALE_F = (float)(2.0 / 65535.0);
    float x = (float)(-t) * ds;
    float e;
    if (x >= 0.0f) {
      float y0 = expf(0.0f), y1 = expf(1.0f);
      e = rintf((y0 + x * ((y1 - y0) / 1.0f)) / EXP_SCALE_F);
    } else if (x >= -10.0f) {
      float delta = 10.0f / 255.0f;
      float idxf = rintf((x + 10.0f) * 25.5f);
      idxf = fminf(fmaxf(idxf, 0.0f), 255.0f);
      float xs = -10.0f + idxf * delta;
      e = rintf((float)exp((double)xs) / EXP_SCALE_F);
    } else {
      float delta = 10.0f / 255.0f;
      float idxf = rintf((x + 20.0f) * 25.5f);
      idxf = fminf(fmaxf(idxf, 0.0f), 255.0f);
      float xs = -20.0f + idxf * delta;
      e = rintf((float)exp((double)xs) / EXP_SCALE_F);
    }
    e = fminf(fmaxf(e, -32768.0f), 32767.0f);
    exp_tab_f[t] = e;                // integer-valued float in [0, 32767]

    const float RECIP_SCALE_F = (float)((1.0 / 0.1) * 2.0 / 65535.0);
    float deltar = (250.0f - 0.1f) / 255.0f;
    float xs = 0.1f + (float)t * deltar;
    float r = rintf((1.0f / xs) / RECIP_SCALE_F);
    r = fminf(fmaxf(r, -32768.0f), 32767.0f);
    recip_tab[t] = r;
  }
  __syncthreads();   // the only barrier

  // ---- load 8 channels x 4 pixels; pack bytes; in-lane max ----
  const int blk   = blockIdx.x;
  const int b     = blk / BPB;
  const int base4 = b * NC * (NHW / 4) + (blk % BPB) * (PIX / 4) + q;
  const int4* g4  = (const int4*)data;

  int pd[8];
  int4 m = make_int4(-128, -128, -128, -128);
#pragma unroll
  for (int i = 0; i < 8; ++i) {
    int4 v = g4[base4 + (16 * i + k) * (NHW / 4)];
    m.x = max(m.x, v.x); m.y = max(m.y, v.y);
    m.z = max(m.z, v.z); m.w = max(m.w, v.w);
    pd[i] = (v.x & 255) | ((v.y & 255) << 8) | ((v.z & 255) << 16) |
            (int)((unsigned)(v.w & 255) << 24);
  }

  // ---- DPP butterfly max over the 16 k-lanes (VALU pipe, no LDS) ----
  dpp_max4<DPP_XOR1>(m);
  dpp_max4<DPP_XOR2>(m);
  dpp_max4<DPP_ROR4>(m);
  dpp_max4<DPP_ROR8>(m);

  // ---- in-place packed bytes -> packed j = (q - c) mod 256, per-pixel max --
  // Even bytes (pixels x,z) with borrow guards at bit8/bit24; odd bytes
  // (pixels y,w) guard at bit16, byte3's borrow exits bit31 (mod 2^32).
  {
    unsigned Qe = (((unsigned)m.x & 255u) | (((unsigned)m.z & 255u) << 16)) + 0x01000100u;
    unsigned Qo = ((((unsigned)m.y & 255u) << 8) | (((unsigned)m.w & 255u) << 24)) + 0x00010000u;
#pragma unroll
    for (int i = 0; i < 8; ++i) {
      unsigned pp = (unsigned)pd[i];
      unsigned je = (Qe - (pp & 0x00FF00FFu)) & 0x00FF00FFu;
      unsigned jo = (Qo - (pp & 0xFF00FF00u)) & 0xFF00FF00u;
      pd[i] = (int)(je | jo);
    }
  }

  // ---- exp gather (the only DS-pipe traffic); pack u16 pairs; int sum ----
  int pe[16];
  int4 s = make_int4(0, 0, 0, 0);
#pragma unroll
  for (int i = 0; i < 8; ++i) {
    unsigned J = (unsigned)pd[i];
    int e0 = (int)exp_tab_f[J & 255u];
    int e1 = (int)exp_tab_f[(J >> 8) & 255u];
    int e2 = (int)exp_tab_f[(J >> 16) & 255u];
    int e3 = (int)exp_tab_f[J >> 24];
    s.x += e0; s.y += e1; s.z += e2; s.w += e3;
    pe[2 * i]     = e0 | (e1 << 16);   // e in [0,32767], sign-safe
    pe[2 * i + 1] = e2 | (e3 << 16);
  }

  // ---- DPP butterfly sum over the 16 k-lanes (exact int sum < 2^23) ----
  dpp_add4<DPP_XOR1>(s);
  dpp_add4<DPP_XOR2>(s);
  dpp_add4<DPP_ROR4>(s);
  dpp_add4<DPP_ROR8>(s);

  // ---- reciprocal of shifted sum (per-lane redundant; broadcast LDS read) --
  const float DIV_SCALE_F = (float)((2.0 / 65535.0) * 128.0); // exp_scale*2^7
  const float RIDX_K_F    = (float)(255.0 / (250.0 - 0.1));
  float rq[4];
  {
    int tv[4] = {s.x, s.y, s.z, s.w};
#pragma unroll
    for (int j = 0; j < 4; ++j) {
      float ss = rintf((float)tv[j] * 0.0078125f);   // exact: tv < 2^23
      ss = fminf(fmaxf(ss, -32768.0f), 32767.0f);
      float v = ss * DIV_SCALE_F;
      float idxf = rintf((v - 0.1f) * RIDX_K_F);
      idxf = fminf(fmaxf(idxf, 0.0f), 255.0f);
      rq[j] = recip_tab[(int)idxf];
    }
  }

  // ---- epilogue: out = clip(round((e*rq)*K), -128, 127) * OUT_SCALE ----
  const float K_F = (float)((2.0 / 65535.0) * ((1.0 / 0.1) * 2.0 / 65535.0) / (2.0 / 255.0));
  const float OUT_SCALE_F = (float)(2.0 / 255.0);
  vfloat4* o4 = (vfloat4*)out;
#pragma unroll
  for (int i = 0; i < 8; ++i) {
    int pa = pe[2 * i], pb = pe[2 * i + 1];
    float e0 = (float)(pa & 0xFFFF);
    float e1 = (float)(pa >> 16);
    float e2 = (float)(pb & 0xFFFF);
    float e3 = (float)(pb >> 16);
    vfloat4 o;
    o.x = fminf(fmaxf(rintf((e0 * rq[0]) * K_F), -128.0f), 127.0f) * OUT_SCALE_F;
    o.y = fminf(fmaxf(rintf((e1 * rq[1]) * K_F), -128.0f), 127.0f) * OUT_SCALE_F;
    o.z = fminf(fmaxf(rintf((e2 * rq[2]) * K_F), -128.0f), 127.0f) * OUT_SCALE_F;
    o.w = fminf(fmaxf(rintf((e3 * rq[3]) * K_F), -128.0f), 127.0f) * OUT_SCALE_F;
    __builtin_nontemporal_store(o, (vfloat4*)&o4[base4 + (16 * i + k) * (NHW / 4)]);
  }
}

extern "C" void kernel_launch(void* const* d_in, const int* in_sizes, int n_in,
                              void* d_out, int out_size, void* d_ws, size_t ws_size,
                              hipStream_t stream) {
  const int* data     = (const int*)d_in[0];
  const float* dscale = (const float*)d_in[1];
  float* out          = (float*)d_out;
  (void)in_sizes; (void)n_in; (void)d_ws; (void)ws_size; (void)out_size;

  dim3 grid(NB * BPB);   // 32 * 100 = 3200 blocks of 256 threads
  qsoftmax_kernel<<<grid, TPB, 0, stream>>>(data, dscale, out);
}

// Round 8
// 188.806 us; speedup vs baseline: 1.0734x; 1.0734x over previous
//
#include <hip/hip_runtime.h>
#include <cmath>

// Shapes fixed by the reference: data [32,128,80,80] int32, scale 0.0625.
#define NB    32
#define NC    128
#define NHW   6400          // 80*80, contiguous per (b,c)
#define PIX   64            // pixels per tile
#define TPB   256           // 16 channel-groups x 16 pixel-quads
#define PAIRS 50            // pairs of 64-px tiles per image -> 2 tiles/block

typedef float vfloat4 __attribute__((ext_vector_type(4)));

// R3 layout (67us best): thread t: k = t>>4 owns channels {k,k+16,...,k+112};
// p4 = t&15 owns pixel-quad p4 -> every global access is 16 lanes x 16B =
// 256B contiguous per channel (R7 showed smaller fragments amplify writes).
// New in R8: each block processes TWO adjacent 64-px tiles; tile1's raw loads
// are issued right after tile0's first barrier and consumed only after
// tile0's recip -> ~8KB in flight across tile0's whole compute phase.

__global__ __launch_bounds__(TPB) void qsoftmax_kernel(
    const int* __restrict__ data,
    const float* __restrict__ dscale,
    float* __restrict__ out) {
#pragma clang fp contract(off)
  __shared__ int   exp_tab[256];    // quantized exp vs j = qmax - c
  __shared__ float recip_tab[256];  // quantized 1/v table, region (0.1, 250)
  __shared__ int4  red_m[16][16];   // [k][p4] partial max
  __shared__ int4  red_s[16][16];   // [k][p4] partial sum

  const int t  = threadIdx.x;
  const int k  = t >> 4;
  const int p4 = t & 15;
  const float ds = dscale[0];       // 0.0625

  // ---- build LUTs once per block (identical math to the absmax=0 kernel) ----
  {
    const float EXP_SCALE_F = (float)(2.0 / 65535.0);
    float x = (float)(-t) * ds;
    float e;
    if (x >= 0.0f) {
      float y0 = expf(0.0f), y1 = expf(1.0f);
      e = rintf((y0 + x * ((y1 - y0) / 1.0f)) / EXP_SCALE_F);
    } else if (x >= -10.0f) {
      float delta = 10.0f / 255.0f;
      float idxf = rintf((x + 10.0f) * 25.5f);
      idxf = fminf(fmaxf(idxf, 0.0f), 255.0f);
      float xs = -10.0f + idxf * delta;
      e = rintf((float)exp((double)xs) / EXP_SCALE_F);
    } else {
      float delta = 10.0f / 255.0f;
      float idxf = rintf((x + 20.0f) * 25.5f);
      idxf = fminf(fmaxf(idxf, 0.0f), 255.0f);
      float xs = -20.0f + idxf * delta;
      e = rintf((float)exp((double)xs) / EXP_SCALE_F);
    }
    e = fminf(fmaxf(e, -32768.0f), 32767.0f);
    exp_tab[t] = (int)e;

    const float RECIP_SCALE_F = (float)((1.0 / 0.1) * 2.0 / 65535.0);
    float deltar = (250.0f - 0.1f) / 255.0f;
    float xs = 0.1f + (float)t * deltar;
    float r = rintf((1.0f / xs) / RECIP_SCALE_F);
    r = fminf(fmaxf(r, -32768.0f), 32767.0f);
    recip_tab[t] = r;
  }

  const int blk   = blockIdx.x;
  const int b     = blk / PAIRS;
  const int pair  = blk % PAIRS;
  const int base4 = b * NC * (NHW / 4) + pair * 32 + p4;  // tile0; tile1 = +16
  const int4* g4  = (const int4*)data;
  vfloat4* o4     = (vfloat4*)out;

  const float DIV_SCALE_F = (float)((2.0 / 65535.0) * 128.0); // exp_scale*2^7
  const float RIDX_K_F    = (float)(255.0 / (250.0 - 0.1));
  const float K_F = (float)((2.0 / 65535.0) * ((1.0 / 0.1) * 2.0 / 65535.0) / (2.0 / 255.0));
  const float OUT_SCALE_F = (float)(2.0 / 255.0);

  // ---- tile0: load + local max + pack ----
  int pd0[8];
  int4 m0 = make_int4(-128, -128, -128, -128);
#pragma unroll
  for (int i = 0; i < 8; ++i) {
    int4 v = g4[base4 + (16 * i + k) * (NHW / 4)];
    m0.x = max(m0.x, v.x); m0.y = max(m0.y, v.y);
    m0.z = max(m0.z, v.z); m0.w = max(m0.w, v.w);
    pd0[i] = (v.x & 255) | ((v.y & 255) << 8) | ((v.z & 255) << 16) |
             (int)((unsigned)(v.w & 255) << 24);
  }
  red_m[k][p4] = m0;
  __syncthreads();                       // barrier 1 (also covers LUT build)

  // ---- PREFETCH tile1: issue raw loads now, consume after tile0's recip ----
  int4 v1[8];
#pragma unroll
  for (int i = 0; i < 8; ++i) {
    v1[i] = g4[base4 + 16 + (16 * i + k) * (NHW / 4)];
  }

  // ---- tile0: reduce max (broadcast b128 reads, overlaps prefetch) ----
  int4 q = red_m[0][p4];
#pragma unroll
  for (int kk = 1; kk < 16; ++kk) {
    int4 r = red_m[kk][p4];
    q.x = max(q.x, r.x); q.y = max(q.y, r.y);
    q.z = max(q.z, r.z); q.w = max(q.w, r.w);
  }

  // ---- tile0: packed bytes -> packed j = (q - c) mod 256 ----
  {
    unsigned Qe = (((unsigned)q.x & 255u) | (((unsigned)q.z & 255u) << 16)) + 0x01000100u;
    unsigned Qo = ((((unsigned)q.y & 255u) << 8) | (((unsigned)q.w & 255u) << 24)) + 0x00010000u;
#pragma unroll
    for (int i = 0; i < 8; ++i) {
      unsigned pp = (unsigned)pd0[i];
      unsigned je = (Qe - (pp & 0x00FF00FFu)) & 0x00FF00FFu;
      unsigned jo = (Qo - (pp & 0xFF00FF00u)) & 0xFF00FF00u;
      pd0[i] = (int)(je | jo);
    }
  }

  // ---- tile0: exp gather + pack u16 pairs + partial int sum ----
  int pe0[16];
  int4 s0 = make_int4(0, 0, 0, 0);
#pragma unroll
  for (int i = 0; i < 8; ++i) {
    unsigned J = (unsigned)pd0[i];
    int e0 = exp_tab[J & 255u];
    int e1 = exp_tab[(J >> 8) & 255u];
    int e2 = exp_tab[(J >> 16) & 255u];
    int e3 = exp_tab[J >> 24];
    s0.x += e0; s0.y += e1; s0.z += e2; s0.w += e3;
    pe0[2 * i]     = e0 | (e1 << 16);
    pe0[2 * i + 1] = e2 | (e3 << 16);
  }
  red_s[k][p4] = s0;
  __syncthreads();                       // barrier 2

  // ---- tile0: reduce sum + recip ----
  int4 tot = red_s[0][p4];
#pragma unroll
  for (int kk = 1; kk < 16; ++kk) {
    int4 r = red_s[kk][p4];
    tot.x += r.x; tot.y += r.y; tot.z += r.z; tot.w += r.w;
  }
  float rq0[4];
  {
    int tv[4] = {tot.x, tot.y, tot.z, tot.w};
#pragma unroll
    for (int j = 0; j < 4; ++j) {
      float ss = rintf((float)tv[j] * 0.0078125f);
      ss = fminf(fmaxf(ss, -32768.0f), 32767.0f);
      float v = ss * DIV_SCALE_F;
      float idxf = rintf((v - 0.1f) * RIDX_K_F);
      idxf = fminf(fmaxf(idxf, 0.0f), 255.0f);
      rq0[j] = recip_tab[(int)idxf];
    }
  }

  // ---- NOW consume the prefetched tile1: local max + pack ----
  int pd1[8];
  int4 m1 = make_int4(-128, -128, -128, -128);
#pragma unroll
  for (int i = 0; i < 8; ++i) {
    int4 v = v1[i];
    m1.x = max(m1.x, v.x); m1.y = max(m1.y, v.y);
    m1.z = max(m1.z, v.z); m1.w = max(m1.w, v.w);
    pd1[i] = (v.x & 255) | ((v.y & 255) << 8) | ((v.z & 255) << 16) |
             (int)((unsigned)(v.w & 255) << 24);
  }
  red_m[k][p4] = m1;                     // red_m reads finished before barrier 2
  __syncthreads();                       // barrier 3

  // ---- tile0 epilogue: stores drain during tile1's gather phase ----
#pragma unroll
  for (int i = 0; i < 8; ++i) {
    int pa = pe0[2 * i], pb = pe0[2 * i + 1];
    float e0 = (float)(pa & 0xFFFF);
    float e1 = (float)(pa >> 16);
    float e2 = (float)(pb & 0xFFFF);
    float e3 = (float)(pb >> 16);
    vfloat4 o;
    o.x = fminf(fmaxf(rintf((e0 * rq0[0]) * K_F), -128.0f), 127.0f) * OUT_SCALE_F;
    o.y = fminf(fmaxf(rintf((e1 * rq0[1]) * K_F), -128.0f), 127.0f) * OUT_SCALE_F;
    o.z = fminf(fmaxf(rintf((e2 * rq0[2]) * K_F), -128.0f), 127.0f) * OUT_SCALE_F;
    o.w = fminf(fmaxf(rintf((e3 * rq0[3]) * K_F), -128.0f), 127.0f) * OUT_SCALE_F;
    __builtin_nontemporal_store(o, &o4[base4 + (16 * i + k) * (NHW / 4)]);
  }

  // ---- tile1: reduce max ----
  int4 q1 = red_m[0][p4];
#pragma unroll
  for (int kk = 1; kk < 16; ++kk) {
    int4 r = red_m[kk][p4];
    q1.x = max(q1.x, r.x); q1.y = max(q1.y, r.y);
    q1.z = max(q1.z, r.z); q1.w = max(q1.w, r.w);
  }
  {
    unsigned Qe = (((unsigned)q1.x & 255u) | (((unsigned)q1.z & 255u) << 16)) + 0x01000100u;
    unsigned Qo = ((((unsigned)q1.y & 255u) << 8) | (((unsigned)q1.w & 255u) << 24)) + 0x00010000u;
#pragma unroll
    for (int i = 0; i < 8; ++i) {
      unsigned pp = (unsigned)pd1[i];
      unsigned je = (Qe - (pp & 0x00FF00FFu)) & 0x00FF00FFu;
      unsigned jo = (Qo - (pp & 0xFF00FF00u)) & 0xFF00FF00u;
      pd1[i] = (int)(je | jo);
    }
  }

  int pe1[16];
  int4 s1 = make_int4(0, 0, 0, 0);
#pragma unroll
  for (int i = 0; i < 8; ++i) {
    unsigned J = (unsigned)pd1[i];
    int e0 = exp_tab[J & 255u];
    int e1 = exp_tab[(J >> 8) & 255u];
    int e2 = exp_tab[(J >> 16) & 255u];
    int e3 = exp_tab[J >> 24];
    s1.x += e0; s1.y += e1; s1.z += e2; s1.w += e3;
    pe1[2 * i]     = e0 | (e1 << 16);
    pe1[2 * i + 1] = e2 | (e3 << 16);
  }
  red_s[k][p4] = s1;                     // red_s reads finished before barrier 3
  __syncthreads();                       // barrier 4

  int4 tot1 = red_s[0][p4];
#pragma unroll
  for (int kk = 1; kk < 16; ++kk) {
    int4 r = red_s[kk][p4];
    tot1.x += r.x; tot1.y += r.y; tot1.z += r.z; tot1.w += r.w;
  }
  float rq1[4];
  {
    int tv[4] = {tot1.x, tot1.y, tot1.z, tot1.w};
#pragma unroll
    for (int j = 0; j < 4; ++j) {
      float ss = rintf((float)tv[j] * 0.0078125f);
      ss = fminf(fmaxf(ss, -32768.0f), 32767.0f);
      float v = ss * DIV_SCALE_F;
      float idxf = rintf((v - 0.1f) * RIDX_K_F);
      idxf = fminf(fmaxf(idxf, 0.0f), 255.0f);
      rq1[j] = recip_tab[(int)idxf];
    }
  }

#pragma unroll
  for (int i = 0; i < 8; ++i) {
    int pa = pe1[2 * i], pb = pe1[2 * i + 1];
    float e0 = (float)(pa & 0xFFFF);
    float e1 = (float)(pa >> 16);
    float e2 = (float)(pb & 0xFFFF);
    float e3 = (float)(pb >> 16);
    vfloat4 o;
    o.x = fminf(fmaxf(rintf((e0 * rq1[0]) * K_F), -128.0f), 127.0f) * OUT_SCALE_F;
    o.y = fminf(fmaxf(rintf((e1 * rq1[1]) * K_F), -128.0f), 127.0f) * OUT_SCALE_F;
    o.z = fminf(fmaxf(rintf((e2 * rq1[2]) * K_F), -128.0f), 127.0f) * OUT_SCALE_F;
    o.w = fminf(fmaxf(rintf((e3 * rq1[3]) * K_F), -128.0f), 127.0f) * OUT_SCALE_F;
    __builtin_nontemporal_store(o, &o4[base4 + 16 + (16 * i + k) * (NHW / 4)]);
  }
}

extern "C" void kernel_launch(void* const* d_in, const int* in_sizes, int n_in,
                              void* d_out, int out_size, void* d_ws, size_t ws_size,
                              hipStream_t stream) {
  const int* data     = (const int*)d_in[0];
  const float* dscale = (const float*)d_in[1];
  float* out          = (float*)d_out;
  (void)in_sizes; (void)n_in; (void)d_ws; (void)ws_size; (void)out_size;

  dim3 grid(NB * PAIRS);   // 32 * 50 = 1600 blocks, 2 tiles each
  qsoftmax_kernel<<<grid, TPB, 0, stream>>>(data, dscale, out);
}